// Round 1
// baseline (1167.117 us; speedup 1.0000x reference)
//
#include <hip/hip_runtime.h>

#define HORIZON 2048
#define B_TOTAL 4096
#define T_OUT 2047            // outputs per batch row (x0 + 2046 scan steps)
#define WAVES_PER_BLOCK 4

// Hardware transcendental helpers (v_exp_f32 = 2^x, v_rcp_f32 = 1/x, ~1 ulp)
__device__ __forceinline__ float hw_exp2(float x) {
    float r;
    asm("v_exp_f32 %0, %1" : "=v"(r) : "v"(x));
    return r;
}
__device__ __forceinline__ float hw_rcp(float x) {
    float r;
    asm("v_rcp_f32 %0, %1" : "=v"(r) : "v"(x));
    return r;
}

// constants
#define TWO_LOG2E   2.8853900817779268f    // 2*log2(e): tanh(a)=1-2/(2^(a*c)+1)
#define NEG_L2E_TAU -24.04491734814939f    // -log2(e)/0.06: sigmoid(z/tau)=1/(1+2^(z*c))

__global__ __launch_bounds__(256) void thermostat_scan(
    const float* __restrict__ d,
    const float* __restrict__ W1,
    const float* __restrict__ b1,
    const float* __restrict__ W2,
    const float* __restrict__ b2,
    float* __restrict__ xs,
    float* __restrict__ us)
{
    __shared__ float lds[WAVES_PER_BLOCK][HORIZON];
    const int lane = threadIdx.x & 63;
    const int wave = threadIdx.x >> 6;
    const int b = blockIdx.x * WAVES_PER_BLOCK + wave;

    // Stage this wave's d-row into LDS, coalesced float4 (8 iters x 1KB/wave)
    {
        const float4* src = (const float4*)(d + (size_t)b * HORIZON);
        float4* dst = (float4*)lds[wave];
#pragma unroll
        for (int i = 0; i < HORIZON / (64 * 4); ++i)
            dst[lane + 64 * i] = src[lane + 64 * i];
    }
    __syncthreads();

    // Per-lane weights: lane j owns hidden unit j
    const float w10 = W1[lane];          // W1[0, j]
    const float w11 = W1[64 + lane];     // W1[1, j]
    const float b1l = b1[lane];
    const float w20 = W2[2 * lane];      // W2[j, 0]
    const float w21 = W2[2 * lane + 1];  // W2[j, 1]
    const float b20 = b2[0];
    const float b21 = b2[1];

    float* xs_row = xs + (size_t)b * T_OUT;
    float* us_row = us + (size_t)b * T_OUT;

    const float* row = lds[wave];
    float x = row[0];          // x0 = d[b, 0]
    float keep_x = x;          // lane 0 slot of chunk 0 = x0
    float keep_u = 0.0f;       // lane 0 slot of chunk 0 = 0 (us[b,0]=0)

    auto step = [&](int t) {
        float dt = row[t];                               // wave-uniform broadcast
        float hp = fmaf(x, w10, fmaf(dt, w11, b1l));     // layer-1 pre-activation
        // tanh(hp) = 1 - 2/(exp(2*hp)+1)
        float e  = hw_exp2(hp * TWO_LOG2E);
        float r  = hw_rcp(e + 1.0f);
        float h  = fmaf(-2.0f, r, 1.0f);
        // layer 2 partials
        float p0 = h * w20;
        float p1 = h * w21;
        // 64-lane butterfly sum (both outputs interleaved for ILP)
#pragma unroll
        for (int m = 32; m; m >>= 1) {
            p0 += __shfl_xor(p0, m);
            p1 += __shfl_xor(p1, m);
        }
        float z0 = p0 + b20;                             // u
        float z1 = p1 + b21;
        // u_bin = sigmoid(z1/TAU) = 1/(1 + 2^(z1 * -log2e/tau))
        float e2 = hw_exp2(z1 * NEG_L2E_TAU);
        float ub = hw_rcp(1.0f + e2);
        // x_new = 0.99*x + 0.4*u_bin - dt
        x = fmaf(0.99f, x, fmaf(0.4f, ub, -dt));
        // stash this step's outputs in the owning lane
        bool k = (lane == (t & 63));
        keep_x = k ? x : keep_x;
        keep_u = k ? z0 : keep_u;
    };

    // chunk 0: steps t=1..63 fill lanes 1..63 (lane 0 holds x0 / 0)
#pragma unroll 8
    for (int t = 1; t < 64; ++t) step(t);
    xs_row[lane] = keep_x;
    us_row[lane] = keep_u;

    // chunks 1..30: full 64-step chunks, t = 64..1983
    for (int c = 1; c < 31; ++c) {
        const int base = c * 64;
#pragma unroll 8
        for (int i = 0; i < 64; ++i) step(base + i);
        xs_row[base + lane] = keep_x;
        us_row[base + lane] = keep_u;
    }

    // tail: t = 1984..2046 fills lanes 0..62
#pragma unroll 8
    for (int t = 1984; t < 2047; ++t) step(t);
    if (lane < 63) {
        xs_row[1984 + lane] = keep_x;
        us_row[1984 + lane] = keep_u;
    }
}

extern "C" void kernel_launch(void* const* d_in, const int* in_sizes, int n_in,
                              void* d_out, int out_size, void* d_ws, size_t ws_size,
                              hipStream_t stream) {
    const float* d  = (const float*)d_in[0];
    const float* W1 = (const float*)d_in[1];
    const float* b1 = (const float*)d_in[2];
    const float* W2 = (const float*)d_in[3];
    const float* b2 = (const float*)d_in[4];
    float* xs = (float*)d_out;
    float* us = xs + (size_t)B_TOTAL * T_OUT;

    dim3 grid(B_TOTAL / WAVES_PER_BLOCK);   // 1024 blocks x 256 threads = 4096 waves
    thermostat_scan<<<grid, 256, 0, stream>>>(d, W1, b1, W2, b2, xs, us);
}

// Round 2
// 511.711 us; speedup vs baseline: 2.2808x; 2.2808x over previous
//
#include <hip/hip_runtime.h>

#define HORIZON 2048
#define B_TOTAL 4096
#define T_OUT 2047            // outputs per batch row (x0 + 2046 scan steps)
#define WPB 4                 // waves per block

// Hardware transcendentals (v_exp_f32 = 2^x, v_rcp_f32 = 1/x, ~1 ulp)
__device__ __forceinline__ float hw_exp2(float x) {
    float r;
    asm("v_exp_f32 %0, %1" : "=v"(r) : "v"(x));
    return r;
}
__device__ __forceinline__ float hw_rcp(float x) {
    float r;
    asm("v_rcp_f32 %0, %1" : "=v"(r) : "v"(x));
    return r;
}

// DPP move: result = src[dpp-mapped lane], 0 where source lane invalid
template<int CTRL>
__device__ __forceinline__ float dpp_mov(float v) {
    return __int_as_float(__builtin_amdgcn_update_dpp(
        0, __float_as_int(v), CTRL, 0xF, 0xF, true));
}

// Full-wave64 sum via VALU-pipe DPP; valid result lands in lane 63.
__device__ __forceinline__ float wave_sum63(float v) {
    v += dpp_mov<0x111>(v);  // row_shr:1
    v += dpp_mov<0x112>(v);  // row_shr:2
    v += dpp_mov<0x114>(v);  // row_shr:4
    v += dpp_mov<0x118>(v);  // row_shr:8  -> lane 15/31/47/63 hold row sums
    v += dpp_mov<0x142>(v);  // row_bcast:15 -> lane 31/63 hold 32-lane sums
    v += dpp_mov<0x143>(v);  // row_bcast:31 -> lane 63 holds full sum
    return v;
}
__device__ __forceinline__ float bcast63(float v) {
    return __int_as_float(__builtin_amdgcn_readlane(__float_as_int(v), 63));
}

#define K1  2.8853900817779268f    // 2*log2(e): tanh(a) = 1 - 2/(2^(K1*a)+1)
#define CS -24.04491734814939f     // -log2(e)/0.06: sigmoid(z/tau) = 1/(1+2^(CS*z))

__global__ __launch_bounds__(256) void thermostat_scan(
    const float* __restrict__ d,
    const float* __restrict__ W1,
    const float* __restrict__ b1,
    const float* __restrict__ W2,
    const float* __restrict__ b2,
    float* __restrict__ xs,
    float* __restrict__ us)
{
    __shared__ float lds[WPB][HORIZON];
    const int lane = threadIdx.x & 63;
    const int wave = threadIdx.x >> 6;
    const int b = blockIdx.x * WPB + wave;

    // Stage this wave's d-row into LDS, coalesced float4
    {
        const float4* src = (const float4*)(d + (size_t)b * HORIZON);
        float4* dst = (float4*)lds[wave];
#pragma unroll
        for (int i = 0; i < HORIZON / (64 * 4); ++i)
            dst[lane + 64 * i] = src[lane + 64 * i];
    }
    __syncthreads();

    // Per-lane weights, constants folded:
    const float w10c = W1[lane] * K1;          // K1*W1[0,j]
    const float w11c = W1[64 + lane] * K1;     // K1*W1[1,j]
    const float b1c  = b1[lane] * K1;
    const float w20  = W2[2 * lane];           // W2[j,0]
    const float w21  = W2[2 * lane + 1];       // W2[j,1]
    const float w20m = -2.0f * w20;
    const float w21m = -2.0f * w21;
    // Column sums of W2 (loop-invariant): z = S2 + sum_j q_j, q_j = -2 r_j w2_j
    const float s20 = bcast63(wave_sum63(w20));
    const float s21 = bcast63(wave_sum63(w21));
    const float zb0 = s20 + b2[0];             // added to q0-sum at store time
    const float zb1 = (s21 + b2[1]) * CS;      // folded into sigmoid argument

    float* xs_row = xs + (size_t)b * T_OUT;
    float* us_row = us + (size_t)b * T_OUT;

    const float* row = lds[wave];
    const float4* rowv = (const float4*)row;

    float x = row[0];            // x0
    float keep_x = x;            // chunk-0 lane-0 slot = x0
    float keep_u = -zb0;         // chunk-0 lane-0 slot: (-zb0)+zb0 = 0 at store

    auto step = [&](float dt, int slot) {
        // layer 1 + tanh: h = 1 - 2r, r = 1/(exp2(K1*hp)+1)
        float e  = hw_exp2(fmaf(x, w10c, fmaf(dt, w11c, b1c)));
        float r  = hw_rcp(e + 1.0f);
        // layer-2 partials (constant part hoisted out of loop)
        float q0 = r * w20m;
        float q1 = r * w21m;
        float t1 = wave_sum63(q1);   // critical path
        float t0 = wave_sum63(q0);   // off critical path (only feeds stash)
        float z1 = bcast63(t1);
        float z0 = bcast63(t0);
        // u_bin = sigmoid((z1full)/tau) = 1/(1+2^(CS*z1full)), biases folded in zb1
        float a  = fmaf(z1, CS, zb1);
        float ub = hw_rcp(1.0f + hw_exp2(a));
        // x_new = 0.99x + 0.4*ub - dt
        x = fmaf(0.99f, x, fmaf(0.4f, ub, -dt));
        // stash outputs in owning lane
        bool k = (lane == slot);
        keep_x = k ? x : keep_x;
        keep_u = k ? z0 : keep_u;
    };

    // ---- chunk 0: steps t=1..63 (t=0 is x0, already in keep slots) ----
    {
        // group g=0: t = 1..7
        float4 da = rowv[0], db = rowv[1];
        float dts[8] = {da.x, da.y, da.z, da.w, db.x, db.y, db.z, db.w};
#pragma unroll
        for (int k = 1; k < 8; ++k) step(dts[k], k);
#pragma unroll
        for (int g = 1; g < 8; ++g) {
            float4 a4 = rowv[2 * g], b4 = rowv[2 * g + 1];
            float dg[8] = {a4.x, a4.y, a4.z, a4.w, b4.x, b4.y, b4.z, b4.w};
#pragma unroll
            for (int k = 0; k < 8; ++k) step(dg[k], 8 * g + k);
        }
        xs_row[lane] = keep_x;
        us_row[lane] = keep_u + zb0;
    }

    // ---- chunks 1..30: steps t = 64c .. 64c+63 ----
    for (int c = 1; c < 31; ++c) {
        const int base = c * 64;
#pragma unroll
        for (int g = 0; g < 8; ++g) {
            float4 a4 = rowv[16 * c + 2 * g], b4 = rowv[16 * c + 2 * g + 1];
            float dg[8] = {a4.x, a4.y, a4.z, a4.w, b4.x, b4.y, b4.z, b4.w};
#pragma unroll
            for (int k = 0; k < 8; ++k) step(dg[k], 8 * g + k);
        }
        xs_row[base + lane] = keep_x;
        us_row[base + lane] = keep_u + zb0;
    }

    // ---- chunk 31: steps t = 1984..2046 (63 steps, lanes 0..62) ----
    {
#pragma unroll
        for (int g = 0; g < 7; ++g) {
            float4 a4 = rowv[16 * 31 + 2 * g], b4 = rowv[16 * 31 + 2 * g + 1];
            float dg[8] = {a4.x, a4.y, a4.z, a4.w, b4.x, b4.y, b4.z, b4.w};
#pragma unroll
            for (int k = 0; k < 8; ++k) step(dg[k], 8 * g + k);
        }
        // g=7: t = 2040..2046 only (skip t=2047)
        float4 a4 = rowv[16 * 31 + 14], b4 = rowv[16 * 31 + 15];
        float dg[8] = {a4.x, a4.y, a4.z, a4.w, b4.x, b4.y, b4.z, b4.w};
#pragma unroll
        for (int k = 0; k < 7; ++k) step(dg[k], 56 + k);

        if (lane < 63) {
            xs_row[1984 + lane] = keep_x;
            us_row[1984 + lane] = keep_u + zb0;
        }
    }
}

extern "C" void kernel_launch(void* const* d_in, const int* in_sizes, int n_in,
                              void* d_out, int out_size, void* d_ws, size_t ws_size,
                              hipStream_t stream) {
    const float* d  = (const float*)d_in[0];
    const float* W1 = (const float*)d_in[1];
    const float* b1 = (const float*)d_in[2];
    const float* W2 = (const float*)d_in[3];
    const float* b2 = (const float*)d_in[4];
    float* xs = (float*)d_out;
    float* us = xs + (size_t)B_TOTAL * T_OUT;

    dim3 grid(B_TOTAL / WPB);   // 1024 blocks x 256 threads = 4096 waves
    thermostat_scan<<<grid, 256, 0, stream>>>(d, W1, b1, W2, b2, xs, us);
}

// Round 3
// 222.903 us; speedup vs baseline: 5.2360x; 2.2957x over previous
//
#include <hip/hip_runtime.h>

#define HORIZON 2048
#define B_TOTAL 4096
#define T_OUT 2047

// Hardware transcendentals (v_exp_f32 = 2^x, v_rcp_f32 = 1/x, ~1 ulp)
__device__ __forceinline__ float hw_exp2(float x) {
    float r;
    asm("v_exp_f32 %0, %1" : "=v"(r) : "v"(x));
    return r;
}
__device__ __forceinline__ float hw_rcp(float x) {
    float r;
    asm("v_rcp_f32 %0, %1" : "=v"(r) : "v"(x));
    return r;
}

// DPP-mapped move (VALU pipe)
template<int CTRL>
__device__ __forceinline__ float dpp_mov(float v) {
    return __int_as_float(__builtin_amdgcn_update_dpp(
        0, __float_as_int(v), CTRL, 0xF, 0xF, true));
}

// Sum over each 16-lane DPP row; result uniform across all 16 lanes of the row.
// xor1 (quad_perm[1,0,3,2]=0xB1), xor2 (quad_perm[2,3,0,1]=0x4E),
// then rotate-reduce ror:4, ror:8 (valid because values are quad-uniform).
__device__ __forceinline__ float rowsum16(float v) {
    v += dpp_mov<0xB1>(v);
    v += dpp_mov<0x4E>(v);
    v += dpp_mov<0x124>(v);  // row_ror:4
    v += dpp_mov<0x128>(v);  // row_ror:8
    return v;
}

#define K1  2.8853900817779268f    // 2*log2(e): tanh(a) = 1 - 2/(2^(K1*a)+1)
#define CS -24.04491734814939f     // -log2(e)/0.06: sigmoid(z/tau) = 1/(1+2^(CS*z))

__global__ __launch_bounds__(64) void thermostat_scan4(
    const float* __restrict__ d,
    const float* __restrict__ W1,
    const float* __restrict__ b1,
    const float* __restrict__ W2,
    const float* __restrict__ b2,
    float* __restrict__ xs,
    float* __restrict__ us)
{
    const int lane = threadIdx.x;        // 0..63
    const int sub  = lane >> 4;          // batch row within wave (0..3)
    const int pos  = lane & 15;          // lane position within 16-row
    const int grow = blockIdx.x * 4 + sub;

    const float* drow = d + (size_t)grow * HORIZON;
    const float4* dv  = (const float4*)drow;

    // Each lane owns hidden units j = pos + 16k, k=0..3. Constants folded.
    float w10c[4], w11c[4], b1c[4], w20m[4], w21m[4];
    float s20p = 0.f, s21p = 0.f;
#pragma unroll
    for (int k = 0; k < 4; ++k) {
        int j = pos + 16 * k;
        w10c[k] = W1[j] * K1;
        w11c[k] = W1[64 + j] * K1;
        b1c[k]  = b1[j] * K1;
        float a0 = W2[2 * j], a1 = W2[2 * j + 1];
        w20m[k] = -2.f * a0;
        w21m[k] = -2.f * a1;
        s20p += a0;
        s21p += a1;
    }
    // Column sums of W2 (identical for every row): z = zb + sum_j(-2 r_j w_j)
    const float zb0  = rowsum16(s20p) + b2[0];
    const float zb1c = (rowsum16(s21p) + b2[1]) * CS;   // folded into sigmoid arg

    float* xs_p = xs + (size_t)grow * T_OUT + pos;
    float* us_p = us + (size_t)grow * T_OUT + pos;

    // chunk 0 data (t=0..15); element 0 is x0
    float4 c0 = dv[0], c1 = dv[1], c2 = dv[2], c3 = dv[3];
    // prefetch chunk 1
    float4 n0 = dv[4], n1 = dv[5], n2 = dv[6], n3 = dv[7];

    float x = c0.x;                 // x0 (uniform within 16-row)
    float keep_x = x;               // pos-0 slot of chunk 0
    float keep_u = -zb0;            // (+zb0 at store) = 0

    auto step = [&](float dt, int slot) {
        // layer 1 + tanh for 4 units: r_k = 1/(exp2(K1*a_k)+1), h = 1-2r
        float e0 = hw_exp2(fmaf(x, w10c[0], fmaf(dt, w11c[0], b1c[0])));
        float e1 = hw_exp2(fmaf(x, w10c[1], fmaf(dt, w11c[1], b1c[1])));
        float e2 = hw_exp2(fmaf(x, w10c[2], fmaf(dt, w11c[2], b1c[2])));
        float e3 = hw_exp2(fmaf(x, w10c[3], fmaf(dt, w11c[3], b1c[3])));
        float r0 = hw_rcp(e0 + 1.f);
        float r1 = hw_rcp(e1 + 1.f);
        float r2 = hw_rcp(e2 + 1.f);
        float r3 = hw_rcp(e3 + 1.f);
        // column partials, tree-combined (constant part hoisted into zb*)
        float q1a = fmaf(r1, w21m[1], r0 * w21m[0]);
        float q1b = fmaf(r3, w21m[3], r2 * w21m[2]);
        float z1  = rowsum16(q1a + q1b);        // critical path
        float q0a = fmaf(r1, w20m[1], r0 * w20m[0]);
        float q0b = fmaf(r3, w20m[3], r2 * w20m[2]);
        float z0  = rowsum16(q0a + q0b);        // off critical path
        // u_bin = 1/(1+2^(CS*z1full)); biases pre-folded in zb1c
        float ub = hw_rcp(1.f + hw_exp2(fmaf(z1, CS, zb1c)));
        // x_new = 0.99x + 0.4 ub - dt   (uniform within 16-row)
        x = fmaf(0.99f, x, fmaf(0.4f, ub, -dt));
        // stash outputs in the owning lane
        bool k = (pos == slot);
        keep_x = k ? x : keep_x;
        keep_u = k ? z0 : keep_u;
    };

    // ---- chunk 0: steps t=1..15 (slot 0 holds x0 / 0) ----
    {
        float dt16[16] = {c0.x, c0.y, c0.z, c0.w, c1.x, c1.y, c1.z, c1.w,
                          c2.x, c2.y, c2.z, c2.w, c3.x, c3.y, c3.z, c3.w};
#pragma unroll
        for (int s = 1; s < 16; ++s) step(dt16[s], s);
        xs_p[0] = keep_x;
        us_p[0] = keep_u + zb0;
    }

    // ---- chunks 1..126 (16 steps each), prefetch chunk c+1 ----
    for (int c = 1; c < 127; ++c) {
        c0 = n0; c1 = n1; c2 = n2; c3 = n3;
        n0 = dv[4 * c + 4]; n1 = dv[4 * c + 5];
        n2 = dv[4 * c + 6]; n3 = dv[4 * c + 7];
        float dt16[16] = {c0.x, c0.y, c0.z, c0.w, c1.x, c1.y, c1.z, c1.w,
                          c2.x, c2.y, c2.z, c2.w, c3.x, c3.y, c3.z, c3.w};
#pragma unroll
        for (int s = 0; s < 16; ++s) step(dt16[s], s);
        xs_p[c * 16] = keep_x;
        us_p[c * 16] = keep_u + zb0;
    }

    // ---- chunk 127: steps t=2032..2046 (15 steps, slots 0..14) ----
    {
        float dt16[16] = {n0.x, n0.y, n0.z, n0.w, n1.x, n1.y, n1.z, n1.w,
                          n2.x, n2.y, n2.z, n2.w, n3.x, n3.y, n3.z, n3.w};
#pragma unroll
        for (int s = 0; s < 15; ++s) step(dt16[s], s);
        if (pos < 15) {
            xs_p[127 * 16] = keep_x;
            us_p[127 * 16] = keep_u + zb0;
        }
    }
}

extern "C" void kernel_launch(void* const* d_in, const int* in_sizes, int n_in,
                              void* d_out, int out_size, void* d_ws, size_t ws_size,
                              hipStream_t stream) {
    const float* d  = (const float*)d_in[0];
    const float* W1 = (const float*)d_in[1];
    const float* b1 = (const float*)d_in[2];
    const float* W2 = (const float*)d_in[3];
    const float* b2 = (const float*)d_in[4];
    float* xs = (float*)d_out;
    float* us = xs + (size_t)B_TOTAL * T_OUT;

    dim3 grid(B_TOTAL / 4);   // 1024 blocks x 1 wave, 4 batch rows per wave
    thermostat_scan4<<<grid, 64, 0, stream>>>(d, W1, b1, W2, b2, xs, us);
}